// Round 5
// baseline (255.420 us; speedup 1.0000x reference)
//
#include <hip/hip_runtime.h>
#include <math.h>

// B=4, C=256 -> 4 groups x 64ch. H=W=128. img = g*4 + bb.
#define Hs 128
#define Ws 128
#define HWs 16384

typedef __attribute__((ext_vector_type(8))) short short8;
typedef __attribute__((ext_vector_type(8))) __bf16 bf16x8;
typedef __attribute__((ext_vector_type(4))) float f32x4;
typedef __attribute__((ext_vector_type(2))) float f32x2;

static __device__ __forceinline__ float bf2f(unsigned short u) {
    union { unsigned int i; float f; } v; v.i = ((unsigned int)u) << 16; return v.f;
}
// round-to-nearest-even fp32 -> bf16 (finite inputs)
static __device__ __forceinline__ unsigned short f2bf(float f) {
    unsigned int u = __builtin_bit_cast(unsigned int, f);
    return (unsigned short)((u + 0x7fffu + ((u >> 16) & 1u)) >> 16);
}
static __device__ __forceinline__ f32x4 mfma16(short8 a, short8 b, f32x4 c) {
    return __builtin_amdgcn_mfma_f32_16x16x32_bf16(
        __builtin_bit_cast(bf16x8, a), __builtin_bit_cast(bf16x8, b), c, 0, 0, 0);
}
// packed 2xf32 ops (VOP3P)
static __device__ __forceinline__ f32x2 pk_mul(f32x2 a, f32x2 b) {
    f32x2 d;
    asm("v_pk_mul_f32 %0, %1, %2" : "=v"(d) : "v"(a), "v"(b));
    return d;
}
static __device__ __forceinline__ f32x2 pk_fma(f32x2 a, f32x2 b, f32x2 c) {
    f32x2 d;
    asm("v_pk_fma_f32 %0, %1, %2, %3" : "=v"(d) : "v"(a), "v"(b), "v"(c));
    return d;
}
// single-instruction RNE pack of two f32 -> bf16x2 (== f2bf pair bit-exactly)
static __device__ __forceinline__ unsigned int cvt_pk_bf16(float lo, float hi) {
    unsigned int d;
    asm("v_cvt_pk_bf16_f32 %0, %1, %2" : "=v"(d) : "v"(lo), "v"(hi));
    return d;
}
// dword of 2 packed bf16 -> f32x2 {lo, hi}
static __device__ __forceinline__ f32x2 bfpair(unsigned int u) {
    union { unsigned int i[2]; f32x2 f; } v;
    v.i[0] = u << 16;
    v.i[1] = u & 0xffff0000u;
    return v.f;
}
// Workgroup barrier WITHOUT the vmcnt(0) drain __syncthreads() emits.
static __device__ __forceinline__ void barrier_lds_only() {
    asm volatile("s_waitcnt lgkmcnt(0)\n\ts_barrier" ::: "memory");
}

// ---------------------------------------------------------------------------
// k_xt: x [bb][256ch][H][W] fp32 -> xT [img][H*W pixel][64 c] bf16
// (channel-last), with weight-prep fused into the first 576 blocks.
//  w2  [g][64 o][576 ck2] bf16, ck2 = k*64+c
//  wom2[g][32 j][576 ck2] bf16 (j>=27 zero)
//  scsh[0..255]=gamma*rsqrt(var+eps); scsh[256..511]=(b-mean)*sc+beta
// (unchanged from R4)
// ---------------------------------------------------------------------------
__global__ __launch_bounds__(256) void k_xt(const float* __restrict__ x,
                                            const float* __restrict__ w,
                                            const float* __restrict__ b,
                                            const float* __restrict__ w_om,
                                            const float* __restrict__ gamma,
                                            const float* __restrict__ beta,
                                            const float* __restrict__ mean,
                                            const float* __restrict__ var,
                                            unsigned short* __restrict__ xT,
                                            unsigned short* __restrict__ w2,
                                            unsigned short* __restrict__ wom2,
                                            float* __restrict__ scsh) {
    const int tid = threadIdx.x;
    const int f = blockIdx.y * 256 + blockIdx.x;
    // ---- fused prep (first 576 flat blocks) ----
    if (f < 576) {
        int idx = f * 256 + tid;
        if (idx < 4 * 64 * 576) {
            int go = idx / 576;
            int ck = idx - go * 576;
            int k = ck >> 6, c = ck & 63;
            w2[idx] = f2bf(w[go * 576 + c * 9 + k]);
        }
        if (idx < 4 * 32 * 576) {
            int gj = idx / 576;
            int g = gj >> 5, j = gj & 31;
            int ck = idx - gj * 576;
            int k = ck >> 6, c = ck & 63;
            float v = (j < 27) ? w_om[(g * 27 + j) * 576 + c * 9 + k] : 0.f;
            wom2[idx] = f2bf(v);
        }
        if (idx < 256) {
            float sc = gamma[idx] * rsqrtf(var[idx] + 1e-5f);
            scsh[idx] = sc;
            scsh[256 + idx] = (b[idx] - mean[idx]) * sc + beta[idx];
        }
    }

    // ---- transpose/convert ----
    const int img = blockIdx.y;
    const int g = img >> 2, bb = img & 3;
    const int p0 = blockIdx.x * 64;
    __shared__ float t[64 * 65];

    const float* xg = x + (size_t)(bb * 256 + g * 64) * HWs + p0;
    const int l16 = tid & 15, grp = tid >> 4;
#pragma unroll
    for (int pass = 0; pass < 4; ++pass) {
        int c = pass * 16 + grp;
        float4 v = *(const float4*)(xg + (size_t)c * HWs + l16 * 4);
        float* tr = &t[c * 65 + l16 * 4];
        tr[0] = v.x; tr[1] = v.y; tr[2] = v.z; tr[3] = v.w;
    }
    __syncthreads();
    const int p = tid >> 2, c16 = (tid & 3) * 16;
    unsigned short* dst = xT + (size_t)img * HWs * 64 + (size_t)(p0 + p) * 64 + c16;
    unsigned int rr[8];
#pragma unroll
    for (int q = 0; q < 8; ++q)
        rr[q] = cvt_pk_bf16(t[(c16 + 2 * q) * 65 + p], t[(c16 + 2 * q + 1) * 65 + p]);
    *(uint4*)dst       = make_uint4(rr[0], rr[1], rr[2], rr[3]);
    *(uint4*)(dst + 8) = make_uint4(rr[4], rr[5], rr[6], rr[7]);
}

// ---------------------------------------------------------------------------
// R5: FUSED offset-conv + deformable conv + BN + SiLU. k_off is eliminated;
// the 28 MB om HBM round-trip is gone. Each block:
//   1. stage 3x66x64ch bf16 window of xT (bounded: offset conv is a plain
//      3x3 conv), XOR-swizzled like k_off's proven layout
//   2. 32x64 offset-GEMM (wom2) -> bias/sigmoid -> om_l[27][64] in LDS
//   3. Phase A (pO/pW) reads om_l instead of global om
//   4. tap loop / combine / MFMA / epilogue: textually R4 (bit-identical)
// val[2] double-buffers alias the dead window buffer (union) -> LDS 51,200 B.
// ---------------------------------------------------------------------------
__global__ __launch_bounds__(256, 2) void k_def(const unsigned short* __restrict__ xT,
                                                const unsigned short* __restrict__ wom2,
                                                const float* __restrict__ b_om,
                                                const unsigned short* __restrict__ w2,
                                                const float* __restrict__ scsh,
                                                float* __restrict__ out) {
    const int img = blockIdx.y;
    const int g = img >> 2, bb = img & 3;
    const int p0 = blockIdx.x * 64;
    const int hrow = blockIdx.x >> 1;          // image row of this 64-px strip
    const int xh = (blockIdx.x & 1) << 6;      // 0 or 64: which half-row
    const int tid = threadIdx.x;
    const int lane = tid & 63, wv = tid >> 6;
    const int m = lane & 15, q = lane >> 4;

    // xw window (25,344 B) -- reused as val[2][64*64] (16,384 B) after step 2
    __shared__ __align__(16) unsigned short xwv[3 * 66 * 64];
    __shared__ float om_l[27 * 64];            // 6,912 B
    __shared__ int   pO[4][576];
    __shared__ float pW[4][576];
    __shared__ float lsc[64], lsh[64];

    if (tid < 64) {
        lsc[tid] = scsh[g * 64 + tid];
        lsh[tid] = scsh[256 + g * 64 + tid];
    }

    const unsigned short* xTi = xT + (size_t)img * HWs * 64;

    // ---- Step 1: stage 3 rows x 66 px x 64 ch window (zero-fill halo) ----
    for (int i = tid; i < 3 * 66 * 8; i += 256) {
        int r = i / 528;
        int rem = i - r * 528;
        int px = rem >> 3, j = rem & 7;
        int gh = hrow + r - 1, gw = xh + px - 1;
        uint4 v = make_uint4(0, 0, 0, 0);
        if (gh >= 0 && gh < Hs && gw >= 0 && gw < Ws)
            v = *(const uint4*)(xTi + (size_t)(gh * Ws + gw) * 64 + j * 8);
        *(uint4*)&xwv[(r * 66 + px) * 64 + ((j ^ (px & 7)) * 8)] = v;
    }

    // offset-GEMM A fragments (this wave's 16 of 32 j-rows, whole K=576)
    const int mt = wv & 1, ct2 = wv >> 1;      // row-tile, col-pair
    short8 aom[18];
    {
        const unsigned short* wbo = wom2 + (size_t)(g * 32 + mt * 16 + m) * 576 + q * 8;
#pragma unroll
        for (int t = 0; t < 18; ++t) aom[t] = *(const short8*)(wbo + t * 32);
    }

    __syncthreads();   // window staged

    // ---- Step 2: offset GEMM (32 x 64px), k_off's proven fragment code ----
    {
        f32x4 accO[2];
#pragma unroll
        for (int t = 0; t < 2; ++t) accO[t] = (f32x4){0.f, 0.f, 0.f, 0.f};
#pragma unroll
        for (int k = 0; k < 9; ++k) {
            const int ki = k / 3, kj = k - ki * 3;
#pragma unroll
            for (int s = 0; s < 2; ++s) {
#pragma unroll
                for (int t = 0; t < 2; ++t) {
                    int px = (ct2 * 2 + t) * 16 + m + kj;   // 0..65 (halo)
                    int gran = (s * 4 + q) ^ (px & 7);
                    short8 bfrag = *(const short8*)&xwv[(ki * 66 + px) * 64 + gran * 8];
                    accO[t] = mfma16(aom[k * 2 + s], bfrag, accO[t]);
                }
            }
        }
        // bias + mask sigmoid -> om_l
#pragma unroll
        for (int t = 0; t < 2; ++t) {
#pragma unroll
            for (int r = 0; r < 4; ++r) {
                int j = mt * 16 + q * 4 + r;
                if (j < 27) {
                    float v = accO[t][r] + b_om[g * 27 + j];
                    if (j >= 18) v = 1.f / (1.f + __expf(-v));
                    om_l[j * 64 + (ct2 * 2 + t) * 16 + m] = v;
                }
            }
        }
    }

    __syncthreads();   // om_l visible; xw window now dead (val may reuse)

    // ---- Phase A: bilinear gather params per (k, pixel), from om_l ----
    for (int idx = tid; idx < 576; idx += 256) {
        int k = idx >> 6, pp = idx & 63;
        int p = p0 + pp;
        int h = p >> 7, w = p & 127;
        float dy = om_l[k * 64 + pp];
        float dx = om_l[(9 + k) * 64 + pp];
        float mk = om_l[(18 + k) * 64 + pp];
        int ki = k / 3, kj = k - ki * 3;
        float py = (float)(h - 1 + ki) + dy;
        float px = (float)(w - 1 + kj) + dx;
        float fy = floorf(py), fx = floorf(px);
        float wy1 = py - fy, wx1 = px - fx;
        float wy0 = 1.f - wy1, wx0 = 1.f - wx1;
        int y0 = (int)fy, x0 = (int)fx, y1 = y0 + 1, x1 = x0 + 1;
        bool vy0 = (y0 >= 0) && (y0 < Hs), vy1 = (y1 >= 0) && (y1 < Hs);
        bool vx0 = (x0 >= 0) && (x0 < Ws), vx1 = (x1 >= 0) && (x1 < Ws);
        int cy0 = min(max(y0, 0), Hs - 1), cy1 = min(max(y1, 0), Hs - 1);
        int cx0 = min(max(x0, 0), Ws - 1), cx1 = min(max(x1, 0), Ws - 1);
        pO[0][idx] = cy0 * Ws + cx0;
        pO[1][idx] = cy0 * Ws + cx1;
        pO[2][idx] = cy1 * Ws + cx0;
        pO[3][idx] = cy1 * Ws + cx1;
        pW[0][idx] = (vy0 && vx0) ? wy0 * wx0 * mk : 0.f;
        pW[1][idx] = (vy0 && vx1) ? wy0 * wx1 * mk : 0.f;
        pW[2][idx] = (vy1 && vx0) ? wy1 * wx0 * mk : 0.f;
        pW[3][idx] = (vy1 && vx1) ? wy1 * wx1 * mk : 0.f;
    }

    f32x4 acc[4];
#pragma unroll
    for (int t = 0; t < 4; ++t) acc[t] = (f32x4){0.f, 0.f, 0.f, 0.f};

    const int p = tid >> 2, c4 = tid & 3;
    const int wr_sw = ((p >> 1) & 7) << 3;       // write-side granule swizzle
    const int rd_sw = ((m >> 1) & 7) << 3;       // read-side (row = t*16+m)

    __syncthreads();   // Phase A (and lsc/lsh) visible — full drain OK here

    // per-tap A-fragment double buffer (2 x short8 = 8 VGPRs per buffer)
    short8 af[2][2];
    const unsigned short* wb = w2 + (size_t)(g * 64 + wv * 16 + m) * 576 + q * 8;
    auto fetchA = [&](int k, int bf) {
        af[bf][0] = *(const short8*)(wb + (k * 2 + 0) * 32);
        af[bf][1] = *(const short8*)(wb + (k * 2 + 1) * 32);
    };

    // double-buffered register gather prefetch:
    // 8 chunks = 4 corners x 2 adjacent 8-ch chunks {2*c4, 2*c4+1}
    uint4 gth[2][8];
    float wfb[2][4];
    auto fetch = [&](int k, int bf) {
        const int kb = k * 64 + p;
        const int off0 = pO[0][kb], off1 = pO[1][kb], off2 = pO[2][kb], off3 = pO[3][kb];
        wfb[bf][0] = pW[0][kb]; wfb[bf][1] = pW[1][kb];
        wfb[bf][2] = pW[2][kb]; wfb[bf][3] = pW[3][kb];
        const unsigned short* s0 = xTi + (size_t)off0 * 64 + c4 * 16;
        const unsigned short* s1 = xTi + (size_t)off1 * 64 + c4 * 16;
        const unsigned short* s2 = xTi + (size_t)off2 * 64 + c4 * 16;
        const unsigned short* s3 = xTi + (size_t)off3 * 64 + c4 * 16;
        gth[bf][0] = *(const uint4*)(s0);
        gth[bf][1] = *(const uint4*)(s1);
        gth[bf][2] = *(const uint4*)(s2);
        gth[bf][3] = *(const uint4*)(s3);
        gth[bf][4] = *(const uint4*)(s0 + 8);
        gth[bf][5] = *(const uint4*)(s1 + 8);
        gth[bf][6] = *(const uint4*)(s2 + 8);
        gth[bf][7] = *(const uint4*)(s3 + 8);
    };
    fetch(0, 0);
    fetchA(0, 0);

#pragma unroll
    for (int k = 0; k < 9; ++k) {
        const int cb = k & 1, nb = cb ^ 1;
        if (k < 8) {
            fetch(k + 1, nb);    // next tap's gathers in flight across barrier
            fetchA(k + 1, nb);   // next tap's A-fragments too
        }
        // ---- combine: packed 2xf32 math on prefetched regs ----
        unsigned short* vb = &xwv[cb * 4096];   // val buffer aliases window
        const float* wf = wfb[cb];
        f32x2 w0p = {wf[0], wf[0]}, w1p = {wf[1], wf[1]};
        f32x2 w2p = {wf[2], wf[2]}, w3p = {wf[3], wf[3]};
#pragma unroll
        for (int it = 0; it < 2; ++it) {
            const int oc8 = (2 * c4 + it) * 8;
            unsigned int rr[4];
#pragma unroll
            for (int e = 0; e < 4; ++e) {
                f32x2 x0 = bfpair(((const unsigned int*)&gth[cb][it * 4 + 0])[e]);
                f32x2 x1 = bfpair(((const unsigned int*)&gth[cb][it * 4 + 1])[e]);
                f32x2 x2 = bfpair(((const unsigned int*)&gth[cb][it * 4 + 2])[e]);
                f32x2 x3 = bfpair(((const unsigned int*)&gth[cb][it * 4 + 3])[e]);
                f32x2 a = pk_mul(x0, w0p);
                a = pk_fma(x1, w1p, a);
                a = pk_fma(x2, w2p, a);
                a = pk_fma(x3, w3p, a);
                rr[e] = cvt_pk_bf16(a[0], a[1]);
            }
            *(uint4*)&vb[p * 64 + (oc8 ^ wr_sw)] = make_uint4(rr[0], rr[1], rr[2], rr[3]);
        }
        barrier_lds_only();   // ds_writes visible; gathers STAY in flight
        // ---- Phase C: MFMA over this 64-wide K chunk ----
        const unsigned short* vr = &xwv[cb * 4096];
#pragma unroll
        for (int s = 0; s < 2; ++s) {
#pragma unroll
            for (int t = 0; t < 4; ++t) {
                const int row = t * 16 + m;
                short8 bfrag = *(const short8*)&vr[row * 64 + ((s * 32 + q * 8) ^ rd_sw)];
                acc[t] = mfma16(af[cb][s], bfrag, acc[t]);
            }
        }
    }

    // ---- Epilogue: BN + SiLU, coalesced dword stores ----
    float* outg = out + ((size_t)bb * 256 + g * 64) * HWs + p0;
#pragma unroll
    for (int t = 0; t < 4; ++t) {
#pragma unroll
        for (int r = 0; r < 4; ++r) {
            int o = wv * 16 + q * 4 + r;
            float y = acc[t][r] * lsc[o] + lsh[o];
            outg[(size_t)o * HWs + t * 16 + m] = y / (1.f + __expf(-y));
        }
    }
}

// ---------------------------------------------------------------------------
extern "C" void kernel_launch(void* const* d_in, const int* in_sizes, int n_in,
                              void* d_out, int out_size, void* d_ws, size_t ws_size,
                              hipStream_t stream) {
    const float* x     = (const float*)d_in[0];
    const float* w     = (const float*)d_in[1];
    const float* b     = (const float*)d_in[2];
    const float* w_om  = (const float*)d_in[3];
    const float* b_om  = (const float*)d_in[4];
    const float* gamma = (const float*)d_in[5];
    const float* beta  = (const float*)d_in[6];
    const float* mean  = (const float*)d_in[7];
    const float* var   = (const float*)d_in[8];
    float* out = (float*)d_out;

    char* ws = (char*)d_ws;
    unsigned short* xT   = (unsigned short*)(ws + 28311552);        // 33,554,432 B
    unsigned short* w2   = (unsigned short*)(ws + 61865984);        //    294,912 B
    unsigned short* wom2 = (unsigned short*)(ws + 62160896);        //    147,456 B
    float* scsh          = (float*)(ws + 62308352);                 //      2,048 B

    hipLaunchKernelGGL(k_xt, dim3(256, 16), dim3(256), 0, stream,
                       x, w, b, w_om, gamma, beta, mean, var, xT, w2, wom2, scsh);
    hipLaunchKernelGGL(k_def, dim3(256, 16), dim3(256), 0, stream,
                       xT, wom2, b_om, w2, scsh, out);
}

// Round 6
// 240.153 us; speedup vs baseline: 1.0636x; 1.0636x over previous
//
#include <hip/hip_runtime.h>
#include <math.h>

// B=4, C=256 -> 4 groups x 64ch. H=W=128. img = g*4 + bb.
#define Hs 128
#define Ws 128
#define HWs 16384

typedef __attribute__((ext_vector_type(8))) short short8;
typedef __attribute__((ext_vector_type(8))) __bf16 bf16x8;
typedef __attribute__((ext_vector_type(4))) float f32x4;
typedef __attribute__((ext_vector_type(2))) float f32x2;

static __device__ __forceinline__ float bf2f(unsigned short u) {
    union { unsigned int i; float f; } v; v.i = ((unsigned int)u) << 16; return v.f;
}
// round-to-nearest-even fp32 -> bf16 (finite inputs)
static __device__ __forceinline__ unsigned short f2bf(float f) {
    unsigned int u = __builtin_bit_cast(unsigned int, f);
    return (unsigned short)((u + 0x7fffu + ((u >> 16) & 1u)) >> 16);
}
static __device__ __forceinline__ f32x4 mfma16(short8 a, short8 b, f32x4 c) {
    return __builtin_amdgcn_mfma_f32_16x16x32_bf16(
        __builtin_bit_cast(bf16x8, a), __builtin_bit_cast(bf16x8, b), c, 0, 0, 0);
}
// packed 2xf32 ops (VOP3P)
static __device__ __forceinline__ f32x2 pk_mul(f32x2 a, f32x2 b) {
    f32x2 d;
    asm("v_pk_mul_f32 %0, %1, %2" : "=v"(d) : "v"(a), "v"(b));
    return d;
}
static __device__ __forceinline__ f32x2 pk_fma(f32x2 a, f32x2 b, f32x2 c) {
    f32x2 d;
    asm("v_pk_fma_f32 %0, %1, %2, %3" : "=v"(d) : "v"(a), "v"(b), "v"(c));
    return d;
}
// single-instruction RNE pack of two f32 -> bf16x2 (== f2bf pair bit-exactly)
static __device__ __forceinline__ unsigned int cvt_pk_bf16(float lo, float hi) {
    unsigned int d;
    asm("v_cvt_pk_bf16_f32 %0, %1, %2" : "=v"(d) : "v"(lo), "v"(hi));
    return d;
}
// dword of 2 packed bf16 -> f32x2 {lo, hi}
static __device__ __forceinline__ f32x2 bfpair(unsigned int u) {
    union { unsigned int i[2]; f32x2 f; } v;
    v.i[0] = u << 16;
    v.i[1] = u & 0xffff0000u;
    return v.f;
}
// Workgroup barrier WITHOUT the vmcnt(0) drain __syncthreads() emits.
static __device__ __forceinline__ void barrier_lds_only() {
    asm volatile("s_waitcnt lgkmcnt(0)\n\ts_barrier" ::: "memory");
}

// ---------------------------------------------------------------------------
// k_xt: x [bb][256ch][H][W] fp32 -> xT [img][H*W pixel][64 c] bf16
// (channel-last), with weight-prep fused into the first 576 blocks.
//  w2  [g][64 o][576 ck2] bf16, ck2 = k*64+c
//  wom2[g][32 j][576 ck2] bf16 (j>=27 zero)
//  scsh[0..255]=gamma*rsqrt(var+eps); scsh[256..511]=(b-mean)*sc+beta
// R6: the 4 transpose loads are issued before any LDS write (batched, one
// vmcnt chain). Everything else R4.
// ---------------------------------------------------------------------------
__global__ __launch_bounds__(256) void k_xt(const float* __restrict__ x,
                                            const float* __restrict__ w,
                                            const float* __restrict__ b,
                                            const float* __restrict__ w_om,
                                            const float* __restrict__ gamma,
                                            const float* __restrict__ beta,
                                            const float* __restrict__ mean,
                                            const float* __restrict__ var,
                                            unsigned short* __restrict__ xT,
                                            unsigned short* __restrict__ w2,
                                            unsigned short* __restrict__ wom2,
                                            float* __restrict__ scsh) {
    const int tid = threadIdx.x;
    const int f = blockIdx.y * 256 + blockIdx.x;
    // ---- fused prep (first 576 flat blocks) ----
    if (f < 576) {
        int idx = f * 256 + tid;
        if (idx < 4 * 64 * 576) {
            int go = idx / 576;
            int ck = idx - go * 576;
            int k = ck >> 6, c = ck & 63;
            w2[idx] = f2bf(w[go * 576 + c * 9 + k]);
        }
        if (idx < 4 * 32 * 576) {
            int gj = idx / 576;
            int g = gj >> 5, j = gj & 31;
            int ck = idx - gj * 576;
            int k = ck >> 6, c = ck & 63;
            float v = (j < 27) ? w_om[(g * 27 + j) * 576 + c * 9 + k] : 0.f;
            wom2[idx] = f2bf(v);
        }
        if (idx < 256) {
            float sc = gamma[idx] * rsqrtf(var[idx] + 1e-5f);
            scsh[idx] = sc;
            scsh[256 + idx] = (b[idx] - mean[idx]) * sc + beta[idx];
        }
    }

    // ---- transpose/convert ----
    const int img = blockIdx.y;
    const int g = img >> 2, bb = img & 3;
    const int p0 = blockIdx.x * 64;
    __shared__ float t[64 * 65];

    const float* xg = x + (size_t)(bb * 256 + g * 64) * HWs + p0;
    const int l16 = tid & 15, grp = tid >> 4;
    float4 vv[4];
#pragma unroll
    for (int pass = 0; pass < 4; ++pass) {
        int c = pass * 16 + grp;
        vv[pass] = *(const float4*)(xg + (size_t)c * HWs + l16 * 4);
    }
#pragma unroll
    for (int pass = 0; pass < 4; ++pass) {
        int c = pass * 16 + grp;
        float* tr = &t[c * 65 + l16 * 4];
        tr[0] = vv[pass].x; tr[1] = vv[pass].y; tr[2] = vv[pass].z; tr[3] = vv[pass].w;
    }
    __syncthreads();
    const int p = tid >> 2, c16 = (tid & 3) * 16;
    unsigned short* dst = xT + (size_t)img * HWs * 64 + (size_t)(p0 + p) * 64 + c16;
    unsigned int rr[8];
#pragma unroll
    for (int q = 0; q < 8; ++q)
        rr[q] = cvt_pk_bf16(t[(c16 + 2 * q) * 65 + p], t[(c16 + 2 * q + 1) * 65 + p]);
    *(uint4*)dst       = make_uint4(rr[0], rr[1], rr[2], rr[3]);
    *(uint4*)(dst + 8) = make_uint4(rr[4], rr[5], rr[6], rr[7]);
}

// ---------------------------------------------------------------------------
// Offset/mask conv as bf16 MFMA GEMM, row-based LDS reuse.
// R6: staging loop made BRANCHLESS + BATCHED (T14). Old form:
//   per iter: if(in-bounds) load; ds_write  -> load inside a branch ->
//   vmcnt(0) round-trip exposed PER ITERATION (~12x serial L2/HBM latency).
// New form: 13 clamped (always-valid) loads issued back-to-back into regs,
// OOB lanes zeroed via cndmask, then 13 guarded ds_writes. One vmcnt chain.
// Output bit-identical (zero-fill preserved).
// ---------------------------------------------------------------------------
__global__ __launch_bounds__(256, 3) void k_off(const unsigned short* __restrict__ xT,
                                                const unsigned short* __restrict__ wom2,
                                                const float* __restrict__ b_om,
                                                float* __restrict__ om) {
    const int img = blockIdx.y;
    const int g = img >> 2;
    const int h = blockIdx.x;
    const int tid = threadIdx.x;
    const int lane = tid & 63, wv = tid >> 6;
    const int mt = wv & 1, nh = wv >> 1;
    const int m = lane & 15, q = lane >> 4;

    __shared__ unsigned short xrow[3 * 130 * 64];   // 49,920 B, XOR-swizzled

    const unsigned short* xTi = xT + (size_t)img * HWs * 64;

    // ---- batched branchless staging: 3*130*8 = 3120 vec-chunks, 13/thread ----
    uint4 stg[13];
#pragma unroll
    for (int u = 0; u < 13; ++u) {
        int i = tid + u * 256;
        int rr = i / 1040;
        int rem = i - rr * 1040;
        int px = rem >> 3, j = rem & 7;
        int gh = h + rr - 1, gw = px - 1;
        int cgh = min(max(gh, 0), Hs - 1), cgw = min(max(gw, 0), Ws - 1);
        uint4 v = *(const uint4*)(xTi + (size_t)(cgh * Ws + cgw) * 64 + j * 8);
        bool inb = (gh >= 0) && (gh < Hs) && (gw >= 0) && (gw < Ws);
        stg[u].x = inb ? v.x : 0u;
        stg[u].y = inb ? v.y : 0u;
        stg[u].z = inb ? v.z : 0u;
        stg[u].w = inb ? v.w : 0u;
    }
#pragma unroll
    for (int u = 0; u < 13; ++u) {
        int i = tid + u * 256;
        if (i < 3120) {
            int rr = i / 1040;
            int rem = i - rr * 1040;
            int px = rem >> 3, j = rem & 7;
            *(uint4*)&xrow[(rr * 130 + px) * 64 + (j ^ (px & 7)) * 8] = stg[u];
        }
    }

    short8 afrag[18];
    const unsigned short* wb = wom2 + (size_t)(g * 32 + mt * 16 + m) * 576 + q * 8;
#pragma unroll
    for (int t = 0; t < 18; ++t) afrag[t] = *(const short8*)(wb + t * 32);

    f32x4 acc[4];
#pragma unroll
    for (int t = 0; t < 4; ++t) acc[t] = (f32x4){0.f, 0.f, 0.f, 0.f};

    __syncthreads();

#pragma unroll
    for (int k = 0; k < 9; ++k) {
        const int ki = k / 3, kj = k - ki * 3;
#pragma unroll
        for (int s = 0; s < 2; ++s) {
#pragma unroll
            for (int t = 0; t < 4; ++t) {
                int px = (nh * 4 + t) * 16 + m + kj;   // halo-shifted column
                int gran = (s * 4 + q) ^ (px & 7);
                short8 bfrag = *(const short8*)&xrow[(ki * 130 + px) * 64 + gran * 8];
                acc[t] = mfma16(afrag[k * 2 + s], bfrag, acc[t]);
            }
        }
    }

    float* omi = om + (size_t)img * 27 * HWs + h * Ws;
#pragma unroll
    for (int t = 0; t < 4; ++t) {
#pragma unroll
        for (int r = 0; r < 4; ++r) {
            int j = mt * 16 + q * 4 + r;
            if (j < 27) {
                float v = acc[t][r] + b_om[g * 27 + j];
                if (j >= 18) v = 1.f / (1.f + __expf(-v));  // mask sigmoid
                omi[(size_t)j * HWs + (nh * 4 + t) * 16 + m] = v;
            }
        }
    }
}

// ---------------------------------------------------------------------------
// Deformable conv as bf16 MFMA GEMM + BN + SiLU. (textually R4 — verified)
// ---------------------------------------------------------------------------
__global__ __launch_bounds__(256, 2) void k_def(const unsigned short* __restrict__ xT,
                                                const float* __restrict__ om,
                                                const unsigned short* __restrict__ w2,
                                                const float* __restrict__ scsh,
                                                float* __restrict__ out) {
    const int img = blockIdx.y;
    const int g = img >> 2, bb = img & 3;
    const int p0 = blockIdx.x * 64;
    const int tid = threadIdx.x;
    const int lane = tid & 63, wv = tid >> 6;
    const int m = lane & 15, q = lane >> 4;

    __shared__ int   pO[4][576];
    __shared__ float pW[4][576];
    __shared__ unsigned short val[2][64 * 64];   // swizzled, stride 64
    __shared__ float lsc[64], lsh[64];

    if (tid < 64) {
        lsc[tid] = scsh[g * 64 + tid];
        lsh[tid] = scsh[256 + g * 64 + tid];
    }

    // ---- Phase A: bilinear gather params per (k, pixel) ----
    const float* omg = om + (size_t)img * 27 * HWs;
    for (int idx = tid; idx < 576; idx += 256) {
        int k = idx >> 6, pp = idx & 63;
        int p = p0 + pp;
        int h = p >> 7, w = p & 127;
        float dy = omg[k * HWs + p];
        float dx = omg[(9 + k) * HWs + p];
        float mk = omg[(18 + k) * HWs + p];
        int ki = k / 3, kj = k - ki * 3;
        float py = (float)(h - 1 + ki) + dy;
        float px = (float)(w - 1 + kj) + dx;
        float fy = floorf(py), fx = floorf(px);
        float wy1 = py - fy, wx1 = px - fx;
        float wy0 = 1.f - wy1, wx0 = 1.f - wx1;
        int y0 = (int)fy, x0 = (int)fx, y1 = y0 + 1, x1 = x0 + 1;
        bool vy0 = (y0 >= 0) && (y0 < Hs), vy1 = (y1 >= 0) && (y1 < Hs);
        bool vx0 = (x0 >= 0) && (x0 < Ws), vx1 = (x1 >= 0) && (x1 < Ws);
        int cy0 = min(max(y0, 0), Hs - 1), cy1 = min(max(y1, 0), Hs - 1);
        int cx0 = min(max(x0, 0), Ws - 1), cx1 = min(max(x1, 0), Ws - 1);
        pO[0][idx] = cy0 * Ws + cx0;
        pO[1][idx] = cy0 * Ws + cx1;
        pO[2][idx] = cy1 * Ws + cx0;
        pO[3][idx] = cy1 * Ws + cx1;
        pW[0][idx] = (vy0 && vx0) ? wy0 * wx0 * mk : 0.f;
        pW[1][idx] = (vy0 && vx1) ? wy0 * wx1 * mk : 0.f;
        pW[2][idx] = (vy1 && vx0) ? wy1 * wx0 * mk : 0.f;
        pW[3][idx] = (vy1 && vx1) ? wy1 * wx1 * mk : 0.f;
    }

    f32x4 acc[4];
#pragma unroll
    for (int t = 0; t < 4; ++t) acc[t] = (f32x4){0.f, 0.f, 0.f, 0.f};

    const unsigned short* xTi = xT + (size_t)img * HWs * 64;
    const int p = tid >> 2, c4 = tid & 3;
    const int wr_sw = ((p >> 1) & 7) << 3;       // write-side granule swizzle
    const int rd_sw = ((m >> 1) & 7) << 3;       // read-side (row = t*16+m)

    __syncthreads();   // Phase A (and lsc/lsh) visible — full drain OK here

    // per-tap A-fragment double buffer (2 x short8 = 8 VGPRs per buffer)
    short8 af[2][2];
    const unsigned short* wb = w2 + (size_t)(g * 64 + wv * 16 + m) * 576 + q * 8;
    auto fetchA = [&](int k, int bf) {
        af[bf][0] = *(const short8*)(wb + (k * 2 + 0) * 32);
        af[bf][1] = *(const short8*)(wb + (k * 2 + 1) * 32);
    };

    // double-buffered register gather prefetch:
    // 8 chunks = 4 corners x 2 adjacent 8-ch chunks {2*c4, 2*c4+1}
    uint4 gth[2][8];
    float wfb[2][4];
    auto fetch = [&](int k, int bf) {
        const int kb = k * 64 + p;
        const int off0 = pO[0][kb], off1 = pO[1][kb], off2 = pO[2][kb], off3 = pO[3][kb];
        wfb[bf][0] = pW[0][kb]; wfb[bf][1] = pW[1][kb];
        wfb[bf][2] = pW[2][kb]; wfb[bf][3] = pW[3][kb];
        const unsigned short* s0 = xTi + (size_t)off0 * 64 + c4 * 16;
        const unsigned short* s1 = xTi + (size_t)off1 * 64 + c4 * 16;
        const unsigned short* s2 = xTi + (size_t)off2 * 64 + c4 * 16;
        const unsigned short* s3 = xTi + (size_t)off3 * 64 + c4 * 16;
        gth[bf][0] = *(const uint4*)(s0);
        gth[bf][1] = *(const uint4*)(s1);
        gth[bf][2] = *(const uint4*)(s2);
        gth[bf][3] = *(const uint4*)(s3);
        gth[bf][4] = *(const uint4*)(s0 + 8);
        gth[bf][5] = *(const uint4*)(s1 + 8);
        gth[bf][6] = *(const uint4*)(s2 + 8);
        gth[bf][7] = *(const uint4*)(s3 + 8);
    };
    fetch(0, 0);
    fetchA(0, 0);

#pragma unroll
    for (int k = 0; k < 9; ++k) {
        const int cb = k & 1, nb = cb ^ 1;
        if (k < 8) {
            fetch(k + 1, nb);    // next tap's gathers in flight across barrier
            fetchA(k + 1, nb);   // next tap's A-fragments too
        }
        // ---- combine: packed 2xf32 math on prefetched regs ----
        unsigned short* vb = &val[cb][0];
        const float* wf = wfb[cb];
        f32x2 w0p = {wf[0], wf[0]}, w1p = {wf[1], wf[1]};
        f32x2 w2p = {wf[2], wf[2]}, w3p = {wf[3], wf[3]};
#pragma unroll
        for (int it = 0; it < 2; ++it) {
            const int oc8 = (2 * c4 + it) * 8;
            unsigned int rr[4];
#pragma unroll
            for (int e = 0; e < 4; ++e) {
                f32x2 x0 = bfpair(((const unsigned int*)&gth[cb][it * 4 + 0])[e]);
                f32x2 x1 = bfpair(((const unsigned int*)&gth[cb][it * 4 + 1])[e]);
                f32x2 x2 = bfpair(((const unsigned int*)&gth[cb][it * 4 + 2])[e]);
                f32x2 x3 = bfpair(((const unsigned int*)&gth[cb][it * 4 + 3])[e]);
                f32x2 a = pk_mul(x0, w0p);
                a = pk_fma(x1, w1p, a);
                a = pk_fma(x2, w2p, a);
                a = pk_fma(x3, w3p, a);
                rr[e] = cvt_pk_bf16(a[0], a[1]);
            }
            *(uint4*)&vb[p * 64 + (oc8 ^ wr_sw)] = make_uint4(rr[0], rr[1], rr[2], rr[3]);
        }
        barrier_lds_only();   // ds_writes visible; gathers STAY in flight
        // ---- Phase C: MFMA over this 64-wide K chunk ----
        const unsigned short* vr = &val[cb][0];
#pragma unroll
        for (int s = 0; s < 2; ++s) {
#pragma unroll
            for (int t = 0; t < 4; ++t) {
                const int row = t * 16 + m;
                short8 bfrag = *(const short8*)&vr[row * 64 + ((s * 32 + q * 8) ^ rd_sw)];
                acc[t] = mfma16(af[cb][s], bfrag, acc[t]);
            }
        }
    }

    // ---- Epilogue: BN + SiLU, coalesced dword stores ----
    float* outg = out + ((size_t)bb * 256 + g * 64) * HWs + p0;
#pragma unroll
    for (int t = 0; t < 4; ++t) {
#pragma unroll
        for (int r = 0; r < 4; ++r) {
            int o = wv * 16 + q * 4 + r;
            float y = acc[t][r] * lsc[o] + lsh[o];
            outg[(size_t)o * HWs + t * 16 + m] = y / (1.f + __expf(-y));
        }
    }
}

// ---------------------------------------------------------------------------
extern "C" void kernel_launch(void* const* d_in, const int* in_sizes, int n_in,
                              void* d_out, int out_size, void* d_ws, size_t ws_size,
                              hipStream_t stream) {
    const float* x     = (const float*)d_in[0];
    const float* w     = (const float*)d_in[1];
    const float* b     = (const float*)d_in[2];
    const float* w_om  = (const float*)d_in[3];
    const float* b_om  = (const float*)d_in[4];
    const float* gamma = (const float*)d_in[5];
    const float* beta  = (const float*)d_in[6];
    const float* mean  = (const float*)d_in[7];
    const float* var   = (const float*)d_in[8];
    float* out = (float*)d_out;

    char* ws = (char*)d_ws;
    float* om            = (float*)ws;                              // 28,311,552 B
    unsigned short* xT   = (unsigned short*)(ws + 28311552);        // 33,554,432 B
    unsigned short* w2   = (unsigned short*)(ws + 61865984);        //    294,912 B
    unsigned short* wom2 = (unsigned short*)(ws + 62160896);        //    147,456 B
    float* scsh          = (float*)(ws + 62308352);                 //      2,048 B

    hipLaunchKernelGGL(k_xt, dim3(256, 16), dim3(256), 0, stream,
                       x, w, b, w_om, gamma, beta, mean, var, xT, w2, wom2, scsh);
    hipLaunchKernelGGL(k_off, dim3(128, 16), dim3(256), 0, stream, xT, wom2, b_om, om);
    hipLaunchKernelGGL(k_def, dim3(256, 16), dim3(256), 0, stream, xT, om, w2, scsh, out);
}